// Round 9
// baseline (204.773 us; speedup 1.0000x reference)
//
#include <hip/hip_runtime.h>
#include <hip/hip_bf16.h>

#define N_TOK 16384
#define C_DIM 256
#define E_NUM 8
#define H_DIM 682
#define H_PAD 768          // 6 * 128 (pad rows/cols are exact zeros)
#define NROWS (N_TOK * 2)  // total expert-assignments (top-2)
#define HB 64              // scatter blocks / hist segments
#define APB (NROWS / HB)   // assignments per block = 512
#define MAXTILE 264        // sum ceil(cnt_e/128) <= 32768/128 + 8 = 264 (= 8*33)

typedef short short8 __attribute__((ext_vector_type(8)));
typedef float floatx4 __attribute__((ext_vector_type(4)));
typedef unsigned int uint;

__device__ inline unsigned short f2bf(float v) {
    union { float f; uint u; } x; x.f = v;
    uint r = (x.u + 0x7fffu + ((x.u >> 16) & 1u)) >> 16;
    return (unsigned short)r;
}
__device__ inline float bf2f(unsigned short v) {
    union { uint u; float f; } x; x.u = ((uint)v) << 16; return x.f;
}

// Async global->LDS 16B/lane. LDS dst: wave-uniform base + lane*16.
__device__ __forceinline__ void load_lds16(const void* g, void* l) {
    __builtin_amdgcn_global_load_lds(
        (const __attribute__((address_space(1))) unsigned int*)g,
        (__attribute__((address_space(3))) unsigned int*)l, 16, 0, 0);
}

// Counted vmcnt waits: wait for current stage, leave next stage in flight.
#define VMCNT8 asm volatile("s_waitcnt vmcnt(8)" ::: "memory")
#define VMCNT6 asm volatile("s_waitcnt vmcnt(6)" ::: "memory")
#define VMCNT0 asm volatile("s_waitcnt vmcnt(0)" ::: "memory")
#define LGKM0  asm volatile("s_waitcnt lgkmcnt(0)" ::: "memory")

#define P13 (E_NUM * H_PAD * (C_DIM / 2))
#define P2  (E_NUM * C_DIM * (H_PAD / 2))
#define WCONV_BLKS ((2 * P13 + P2) / 256)  // 9216 (exact)

// Fused prep: blocks [0, WCONV_BLKS) do weight convert; the rest do the router
// (+ xb = bf16(x)) AND the expert histogram (fused: a router block's 8
// assignments all fall in hist segment rb>>6, so lane 0 atomicAdds directly —
// this deletes the separate hist_kernel + one launch gap).
__global__ __launch_bounds__(256) void prep_kernel(
    const float* __restrict__ w1, const float* __restrict__ w3, const float* __restrict__ w2,
    unsigned short* __restrict__ w1b, unsigned short* __restrict__ w3b,
    unsigned short* __restrict__ w2b,
    const float* __restrict__ x, const float* __restrict__ rw,
    unsigned short* __restrict__ xb, int* __restrict__ as_e, float* __restrict__ as_gate,
    int* __restrict__ block_hist) {
    __shared__ float rws[E_NUM * C_DIM];
    int tid = threadIdx.x;
    if (blockIdx.x < WCONV_BLKS) {
        int idx = blockIdx.x * 256 + tid;
        if (idx < 2 * P13) {
            const float* src = (idx < P13) ? w1 : w3;
            unsigned short* dst = (idx < P13) ? w1b : w3b;
            int i = (idx < P13) ? idx : idx - P13;
            int e = i / (H_PAD * (C_DIM / 2));
            int rem = i - e * (H_PAD * (C_DIM / 2));
            int r = rem / (C_DIM / 2);
            int c2 = rem - r * (C_DIM / 2);
            uint v = 0;
            if (r < H_DIM) {
                const float2 f = *(const float2*)(src + ((size_t)e * H_DIM + r) * C_DIM + c2 * 2);
                v = (uint)f2bf(f.x) | ((uint)f2bf(f.y) << 16);
            }
            ((uint*)dst)[i] = v;
        } else {
            int i = idx - 2 * P13;
            int e = i / (C_DIM * (H_PAD / 2));
            int rem = i - e * (C_DIM * (H_PAD / 2));
            int r = rem / (H_PAD / 2);
            int c2 = rem - r * (H_PAD / 2);
            uint v = 0;
            if (c2 * 2 < H_DIM) {  // H_DIM even -> clean pair boundary
                const float2 f = *(const float2*)(w2 + ((size_t)e * C_DIM + r) * H_DIM + c2 * 2);
                v = (uint)f2bf(f.x) | ((uint)f2bf(f.y) << 16);
            }
            ((uint*)w2b)[i] = v;
        }
        return;
    }
    // ---- router part ----
    for (int i = tid; i < E_NUM * C_DIM; i += 256) rws[i] = rw[i];
    __syncthreads();
    int rb = blockIdx.x - WCONV_BLKS;
    int wave = tid >> 6, lane = tid & 63;
    int t = rb * 4 + wave;
    const float4 xv = *(const float4*)(x + (size_t)t * C_DIM + lane * 4);
    uint2 pk;
    pk.x = (uint)f2bf(xv.x) | ((uint)f2bf(xv.y) << 16);
    pk.y = (uint)f2bf(xv.z) | ((uint)f2bf(xv.w) << 16);
    *(uint2*)(xb + (size_t)t * C_DIM + lane * 4) = pk;
    float p[E_NUM];
#pragma unroll
    for (int e = 0; e < E_NUM; e++) {
        const float* wr = &rws[e * C_DIM + lane * 4];
        p[e] = xv.x * wr[0] + xv.y * wr[1] + xv.z * wr[2] + xv.w * wr[3];
    }
#pragma unroll
    for (int off = 32; off >= 1; off >>= 1) {
#pragma unroll
        for (int e = 0; e < E_NUM; e++) p[e] += __shfl_down(p[e], off, 64);
    }
    if (lane == 0) {
        float m = p[0];
#pragma unroll
        for (int e = 1; e < E_NUM; e++) m = fmaxf(m, p[e]);
        float s = 0.f, q[E_NUM];
#pragma unroll
        for (int e = 0; e < E_NUM; e++) { q[e] = expf(p[e] - m); s += q[e]; }
#pragma unroll
        for (int e = 0; e < E_NUM; e++) q[e] /= s;
        int e0 = 0;
#pragma unroll
        for (int e = 1; e < E_NUM; e++) if (q[e] > q[e0]) e0 = e;
        int e1 = (e0 == 0) ? 1 : 0;
#pragma unroll
        for (int e = 0; e < E_NUM; e++) {
            if (e != e0 && q[e] > q[e1]) e1 = e;
        }
        float g0 = q[e0], g1 = q[e1];
        float denom = g0 + g1 + 1e-9f;
        g0 /= denom; g1 /= denom;
        as_e[t * 2] = e0; as_gate[t * 2] = g0;
        as_e[t * 2 + 1] = e1; as_gate[t * 2 + 1] = g1;
        // fused histogram: this block's assignments all live in segment rb>>6
        int sb = rb >> 6;
        atomicAdd(&block_hist[sb * E_NUM + e0], 1);
        atomicAdd(&block_hist[sb * E_NUM + e1], 1);
    }
}

// Scatter with FUSED SCAN: each of the 64 blocks redundantly scans the 2 KB
// hist table (L2-hot) to get expert offsets + its own cursor bases; block 0
// additionally publishes offsets[9] and the compact tile map tile_base[9].
// Deletes scan2_kernel + two launch gaps.
__global__ __launch_bounds__(256) void scatter_kernel(
    const int* __restrict__ as_e, const int* __restrict__ block_hist,
    int* __restrict__ offsets, int* __restrict__ tile_base,
    int* __restrict__ row_token, int* __restrict__ as_row) {
    __shared__ int tot_s[E_NUM], pre_s[E_NUM], off_s[E_NUM], cur[E_NUM];
    int b = blockIdx.x, tid = threadIdx.x;
    if (tid < E_NUM) {
        int e = tid, tot = 0, pre = 0;
        for (int bb = 0; bb < HB; bb++) {
            int v = block_hist[bb * E_NUM + e];
            if (bb < b) pre += v;
            tot += v;
        }
        tot_s[e] = tot; pre_s[e] = pre;
    }
    __syncthreads();
    if (tid == 0) {
        int acc = 0;
        for (int i = 0; i < E_NUM; i++) { off_s[i] = acc; acc += tot_s[i]; }
        if (b == 0) {
            int tb = 0; tile_base[0] = 0;
            for (int i = 0; i < E_NUM; i++) {
                offsets[i] = off_s[i];
                tb += (tot_s[i] + 127) / 128;
                tile_base[i + 1] = tb;
            }
            offsets[E_NUM] = acc;
        }
    }
    __syncthreads();
    if (tid < E_NUM) cur[tid] = off_s[tid] + pre_s[tid];
    __syncthreads();
    for (int i = tid; i < APB; i += 256) {
        int a = b * APB + i;
        int e = as_e[a];
        int p = atomicAdd(&cur[e], 1);
        row_token[p] = a >> 1;
        as_row[a] = p;
    }
}

// Map compact tile id -> expert. 7 scalar compares on tile_base[].
__device__ __forceinline__ int tile_to_expert(const int* __restrict__ tile_base, int bid) {
    int e = 0;
#pragma unroll
    for (int i = 1; i < E_NUM; i++) e += (bid >= tile_base[i]) ? 1 : 0;
    return e;
}

// ---------------- Pass 1: h = silu(x.w1^T) * (x.w3^T) ----------------
// BYTE-IDENTICAL to round-8 verified version (47.4 us, FETCH 34.5 MB).
// XCD-aware 1D grid: xcd = bid&7; local = bid>>3; t = (local/6)*8 + xcd;
// c = local%6 — all 6 col-chunks of a row-tile on the SAME XCD (private L2),
// so the gathered A-tile is L2-served for chunks 1..5 (round 8: FETCH 59->34.5 MB).
// launch_bounds stays (256,2) — (256,3) spills the accumulator (round 3).
__global__ __launch_bounds__(256, 2) void expert_ffn1(
    const unsigned short* __restrict__ xb, const unsigned short* __restrict__ w1b,
    const unsigned short* __restrict__ w3b, const int* __restrict__ offsets,
    const int* __restrict__ tile_base, const int* __restrict__ row_token,
    unsigned short* __restrict__ h) {
    int bid = blockIdx.x;            // 0..1583
    int xcd = bid & 7;
    int local = bid >> 3;            // 0..197
    int tq = local / 6;              // 0..32
    int c = local - tq * 6;          // 0..5
    int t = tq * 8 + xcd;            // tile id 0..263
    if (t >= tile_base[E_NUM]) return;
    int e = tile_to_expert(tile_base, t);
    int mt = t - tile_base[e];
    int off0 = offsets[e], off1 = offsets[e + 1];
    int row0 = off0 + mt * 128;
    int mval = min(128, off1 - row0);

    __shared__ union {
        unsigned short buf[2][12288];
        unsigned short Hs[128 * 136];  // 34816 B (overlaps buffers)
    } sm;

    int tid = threadIdx.x, lane = tid & 63, w = tid >> 6;
    int wm = w & 1, wn = w >> 1;
    int ra = tid >> 2;                              // staging row (round 0); +64 for round 1
    int acol = (((tid & 3) ^ ((ra >> 1) & 3))) * 8; // XOR-swizzled 16B source chunk
    int tok0 = row_token[row0 + min(ra, mval - 1)];
    int tok1 = row_token[row0 + min(ra + 64, mval - 1)];
    const unsigned short* a0p = xb + (size_t)tok0 * C_DIM + acol;
    const unsigned short* a1p = xb + (size_t)tok1 * C_DIM + acol;
    const unsigned short* b1p0 = w1b + ((size_t)e * H_PAD + c * 128 + ra) * C_DIM + acol;
    const unsigned short* b1p1 = b1p0 + (size_t)64 * C_DIM;
    const unsigned short* b3p0 = w3b + ((size_t)e * H_PAD + c * 128 + ra) * C_DIM + acol;
    const unsigned short* b3p1 = b3p0 + (size_t)64 * C_DIM;

    int wofs = w * 512;
    auto stage = [&](int kt, unsigned short* base) {
        int kb = kt * 32;
        load_lds16(a0p + kb, base + wofs);
        load_lds16(a1p + kb, base + 2048 + wofs);
        load_lds16(b1p0 + kb, base + 4096 + wofs);
        load_lds16(b1p1 + kb, base + 6144 + wofs);
        load_lds16(b3p0 + kb, base + 8192 + wofs);
        load_lds16(b3p1 + kb, base + 10240 + wofs);
    };

    int ko = ((lane >> 4) ^ ((lane >> 1) & 3)) * 8;
    int l15 = lane & 15;
    int arowf = wm * 64 + l15;
    int browf = wn * 64 + l15;
    int quad = lane >> 4;

    stage(0, sm.buf[0]);

    floatx4 acc1[4][4], acc3[4][4];
#pragma unroll
    for (int m = 0; m < 4; m++)
#pragma unroll
        for (int n = 0; n < 4; n++) {
            acc1[m][n] = (floatx4){0.f, 0.f, 0.f, 0.f};
            acc3[m][n] = (floatx4){0.f, 0.f, 0.f, 0.f};
        }

#pragma unroll
    for (int kt = 0; kt < 8; kt++) {
        if (kt + 1 < 8) stage(kt + 1, sm.buf[(kt + 1) & 1]);
        if (kt + 1 < 8) { VMCNT6; } else { VMCNT0; }
        __builtin_amdgcn_s_barrier();
        const unsigned short* cur = sm.buf[kt & 1];
        short8 af[4], b1f[4], b3f[4];
#pragma unroll
        for (int m = 0; m < 4; m++) af[m] = *(short8*)&cur[(arowf + m * 16) * 32 + ko];
#pragma unroll
        for (int n = 0; n < 4; n++) {
            b1f[n] = *(short8*)&cur[4096 + (browf + n * 16) * 32 + ko];
            b3f[n] = *(short8*)&cur[8192 + (browf + n * 16) * 32 + ko];
        }
        __builtin_amdgcn_s_setprio(1);
#pragma unroll
        for (int m = 0; m < 4; m++)
#pragma unroll
            for (int n = 0; n < 4; n++) {
                acc1[m][n] = __builtin_amdgcn_mfma_f32_16x16x32_bf16(af[m], b1f[n], acc1[m][n], 0, 0, 0);
                acc3[m][n] = __builtin_amdgcn_mfma_f32_16x16x32_bf16(af[m], b3f[n], acc3[m][n], 0, 0, 0);
            }
        __builtin_amdgcn_s_setprio(0);
        LGKM0;
        __builtin_amdgcn_s_barrier();
    }
    __syncthreads();

    // Epilogue: silu(h1)*h3 -> Hs (bf16) -> coalesced 16B stores
#pragma unroll
    for (int m = 0; m < 4; m++)
#pragma unroll
        for (int n = 0; n < 4; n++)
#pragma unroll
            for (int r = 0; r < 4; r++) {
                float h1 = acc1[m][n][r], h3 = acc3[m][n][r];
                float sv = h1 / (1.0f + __expf(-h1)) * h3;
                sm.Hs[(wm * 64 + m * 16 + quad * 4 + r) * 136 + wn * 64 + n * 16 + l15] = f2bf(sv);
            }
    __syncthreads();
#pragma unroll
    for (int it = 0; it < 8; it++) {
        int s = it * 256 + tid;
        int row = s >> 4, c16 = s & 15;
        if (row < mval)
            *(int4*)(h + (size_t)(row0 + row) * H_PAD + c * 128 + c16 * 8) =
                *(int4*)&sm.Hs[row * 136 + c16 * 8];
    }
}

// ---------------- Pass 2: y = h . w2^T (bf16 y, no atomics) ----------------
// BYTE-IDENTICAL to round-8 verified version. Same XCD-aware mapping: both
// C-chunks of a row-tile on one XCD (L2-shares the 192 KB h-row panel).
// BK=64, 2-deep 64 KB LDS, counted vmcnt(8). launch_bounds (256,2).
__global__ __launch_bounds__(256, 2) void expert_ffn2(
    const unsigned short* __restrict__ h, const unsigned short* __restrict__ w2b,
    const int* __restrict__ offsets, const int* __restrict__ tile_base,
    unsigned short* __restrict__ y) {
    int bid = blockIdx.x;            // 0..527
    int xcd = bid & 7;
    int local = bid >> 3;            // 0..65
    int tq = local >> 1;             // 0..32
    int p = local & 1;               // C chunk
    int t = tq * 8 + xcd;            // tile id 0..263
    if (t >= tile_base[E_NUM]) return;
    int e = tile_to_expert(tile_base, t);
    int mt = t - tile_base[e];
    int off0 = offsets[e], off1 = offsets[e + 1];
    int row0 = off0 + mt * 128;
    int mval = min(128, off1 - row0);

    __shared__ union {
        unsigned short buf[2][16384];
        unsigned short Hs[128 * 136];  // 34816 B
    } sm;

    int tid = threadIdx.x, lane = tid & 63, w = tid >> 6;
    int wm = w & 1, wn = w >> 1;
    int ra = tid >> 2;
    int acol = (((tid & 3) ^ ((ra >> 1) & 3))) * 8;  // XOR-swizzled source chunk
    const unsigned short* ap0 = h + (size_t)(row0 + ra) * H_PAD + acol;
    const unsigned short* ap1 = ap0 + (size_t)64 * H_PAD;
    const unsigned short* bp0 = w2b + ((size_t)e * C_DIM + p * 128 + ra) * H_PAD + acol;
    const unsigned short* bp1 = bp0 + (size_t)64 * H_PAD;

    int wofs = w * 512;
    auto stage = [&](int kt, unsigned short* base) {  // kt in 64-col tiles
        int kb = kt * 64;
#pragma unroll
        for (int kk = 0; kk < 2; kk++) {
            int ks = kb + kk * 32;
            unsigned short* b2 = base + kk * 8192;
            load_lds16(ap0 + ks, b2 + wofs);
            load_lds16(ap1 + ks, b2 + 2048 + wofs);
            load_lds16(bp0 + ks, b2 + 4096 + wofs);
            load_lds16(bp1 + ks, b2 + 6144 + wofs);
        }
    };

    int ko = ((lane >> 4) ^ ((lane >> 1) & 3)) * 8;
    int l15 = lane & 15;
    int arowf = wm * 64 + l15;
    int browf = wn * 64 + l15;
    int quad = lane >> 4;

    stage(0, sm.buf[0]);

    floatx4 acc[4][4];
#pragma unroll
    for (int m = 0; m < 4; m++)
#pragma unroll
        for (int n = 0; n < 4; n++) acc[m][n] = (floatx4){0.f, 0.f, 0.f, 0.f};

#pragma unroll
    for (int kt = 0; kt < H_PAD / 64; kt++) {  // 12
        if (kt + 1 < H_PAD / 64) stage(kt + 1, sm.buf[(kt + 1) & 1]);
        if (kt + 1 < H_PAD / 64) { VMCNT8; } else { VMCNT0; }
        __builtin_amdgcn_s_barrier();
        const unsigned short* cur = sm.buf[kt & 1];
#pragma unroll
        for (int kk = 0; kk < 2; kk++) {
            const unsigned short* c2 = cur + kk * 8192;
            short8 af[4], bf[4];
#pragma unroll
            for (int m = 0; m < 4; m++) af[m] = *(short8*)&c2[(arowf + m * 16) * 32 + ko];
#pragma unroll
            for (int n = 0; n < 4; n++) bf[n] = *(short8*)&c2[4096 + (browf + n * 16) * 32 + ko];
            __builtin_amdgcn_s_setprio(1);
#pragma unroll
            for (int m = 0; m < 4; m++)
#pragma unroll
                for (int n = 0; n < 4; n++)
                    acc[m][n] = __builtin_amdgcn_mfma_f32_16x16x32_bf16(af[m], bf[n], acc[m][n], 0, 0, 0);
            __builtin_amdgcn_s_setprio(0);
        }
        LGKM0;
        __builtin_amdgcn_s_barrier();
    }
    __syncthreads();

    // Epilogue: y chunk (bf16) via Hs transpose
#pragma unroll
    for (int m = 0; m < 4; m++)
#pragma unroll
        for (int n = 0; n < 4; n++)
#pragma unroll
            for (int r = 0; r < 4; r++)
                sm.Hs[(wm * 64 + m * 16 + quad * 4 + r) * 136 + wn * 64 + n * 16 + l15] =
                    f2bf(acc[m][n][r]);
    __syncthreads();
#pragma unroll
    for (int it = 0; it < 8; it++) {
        int s = it * 256 + tid;
        int row = s >> 4, c16 = s & 15;
        if (row < mval)
            *(int4*)(y + (size_t)(row0 + row) * C_DIM + p * 128 + c16 * 8) =
                *(int4*)&sm.Hs[row * 136 + c16 * 8];
    }
}

// Combine: out[t][:] = g0*y[row(2t)][:] + g1*y[row(2t+1)][:]  (fp32 out)
__global__ __launch_bounds__(256) void combine_kernel(
    const unsigned short* __restrict__ y, const int* __restrict__ as_row,
    const float* __restrict__ as_gate, float* __restrict__ out) {
    int tid = threadIdx.x, lane = tid & 63;
    int t = blockIdx.x * 4 + (tid >> 6);
    int r0 = as_row[2 * t], r1 = as_row[2 * t + 1];
    float g0 = as_gate[2 * t], g1 = as_gate[2 * t + 1];
    uint2 a = *(const uint2*)(y + (size_t)r0 * C_DIM + lane * 4);
    uint2 b = *(const uint2*)(y + (size_t)r1 * C_DIM + lane * 4);
    float4 o;
    o.x = g0 * bf2f((unsigned short)(a.x & 0xffff)) + g1 * bf2f((unsigned short)(b.x & 0xffff));
    o.y = g0 * bf2f((unsigned short)(a.x >> 16)) + g1 * bf2f((unsigned short)(b.x >> 16));
    o.z = g0 * bf2f((unsigned short)(a.y & 0xffff)) + g1 * bf2f((unsigned short)(b.y & 0xffff));
    o.w = g0 * bf2f((unsigned short)(a.y >> 16)) + g1 * bf2f((unsigned short)(b.y >> 16));
    *(float4*)(out + (size_t)t * C_DIM + lane * 4) = o;
}

extern "C" void kernel_launch(void* const* d_in, const int* in_sizes, int n_in,
                              void* d_out, int out_size, void* d_ws, size_t ws_size,
                              hipStream_t stream) {
    const float* x = (const float*)d_in[0];
    const float* rw = (const float*)d_in[1];
    const float* w1 = (const float*)d_in[2];
    const float* w2 = (const float*)d_in[3];
    const float* w3 = (const float*)d_in[4];
    float* out = (float*)d_out;

    char* ws = (char*)d_ws;
    size_t o = 0;
    auto alloc = [&](size_t bytes) {
        void* p = ws + o;
        o = (o + bytes + 255) & ~(size_t)255;
        return p;
    };
    unsigned short* xb = (unsigned short*)alloc((size_t)N_TOK * C_DIM * 2);
    unsigned short* w1b = (unsigned short*)alloc((size_t)E_NUM * H_PAD * C_DIM * 2);
    unsigned short* w3b = (unsigned short*)alloc((size_t)E_NUM * H_PAD * C_DIM * 2);
    unsigned short* w2b = (unsigned short*)alloc((size_t)E_NUM * C_DIM * H_PAD * 2);
    unsigned short* hbuf = (unsigned short*)alloc((size_t)(NROWS + 128) * H_PAD * 2);
    unsigned short* ybuf = (unsigned short*)alloc((size_t)NROWS * C_DIM * 2);
    int* offsets = (int*)alloc((E_NUM + 1) * 4);
    int* tile_base = (int*)alloc((E_NUM + 1) * 4);
    int* as_e = (int*)alloc(NROWS * 4);
    float* as_gate = (float*)alloc(NROWS * 4);
    int* row_token = (int*)alloc(NROWS * 4);
    int* as_row = (int*)alloc(NROWS * 4);
    int* block_hist = (int*)alloc(HB * E_NUM * 4);

    hipMemsetAsync(block_hist, 0, HB * E_NUM * 4, stream);
    prep_kernel<<<WCONV_BLKS + N_TOK / 4, 256, 0, stream>>>(
        w1, w3, w2, w1b, w3b, w2b, x, rw, xb, as_e, as_gate, block_hist);
    scatter_kernel<<<HB, 256, 0, stream>>>(as_e, block_hist, offsets, tile_base,
                                           row_token, as_row);

    expert_ffn1<<<6 * MAXTILE, 256, 0, stream>>>(xb, w1b, w3b, offsets, tile_base,
                                                 row_token, hbuf);
    expert_ffn2<<<2 * MAXTILE, 256, 0, stream>>>(hbuf, w2b, offsets, tile_base, ybuf);
    combine_kernel<<<N_TOK / 4, 256, 0, stream>>>(ybuf, as_row, as_gate, out);
}

// Round 10
// 179.044 us; speedup vs baseline: 1.1437x; 1.1437x over previous
//
#include <hip/hip_runtime.h>
#include <hip/hip_bf16.h>

#define N_TOK 16384
#define C_DIM 256
#define E_NUM 8
#define H_DIM 682
#define H_PAD 768          // 6 * 128 (pad rows/cols are exact zeros)
#define NROWS (N_TOK * 2)  // total expert-assignments (top-2)
#define HB 64              // histogram/scatter blocks
#define APB (NROWS / HB)   // assignments per block = 512
#define MAXTILE 264        // sum ceil(cnt_e/128) <= 32768/128 + 8 = 264 (= 8*33)

typedef short short8 __attribute__((ext_vector_type(8)));
typedef float floatx4 __attribute__((ext_vector_type(4)));
typedef unsigned int uint;

__device__ inline unsigned short f2bf(float v) {
    union { float f; uint u; } x; x.f = v;
    uint r = (x.u + 0x7fffu + ((x.u >> 16) & 1u)) >> 16;
    return (unsigned short)r;
}
__device__ inline float bf2f(unsigned short v) {
    union { uint u; float f; } x; x.u = ((uint)v) << 16; return x.f;
}
__device__ inline uint pk2(float a, float b) {
    return (uint)f2bf(a) | ((uint)f2bf(b) << 16);
}

// Async global->LDS 16B/lane. LDS dst: wave-uniform base + lane*16.
__device__ __forceinline__ void load_lds16(const void* g, void* l) {
    __builtin_amdgcn_global_load_lds(
        (const __attribute__((address_space(1))) unsigned int*)g,
        (__attribute__((address_space(3))) unsigned int*)l, 16, 0, 0);
}

// Counted vmcnt waits: wait for current stage, leave next stage in flight.
#define VMCNT8 asm volatile("s_waitcnt vmcnt(8)" ::: "memory")
#define VMCNT6 asm volatile("s_waitcnt vmcnt(6)" ::: "memory")
#define VMCNT0 asm volatile("s_waitcnt vmcnt(0)" ::: "memory")
#define LGKM0  asm volatile("s_waitcnt lgkmcnt(0)" ::: "memory")

#define P13 (E_NUM * H_PAD * (C_DIM / 2))   // 786432 uints per w1b/w3b
#define P2  (E_NUM * C_DIM * (H_PAD / 2))   // 786432 uints for w2b
#define NQUAD ((2 * P13 + P2) / 4)          // 589824 quad-groups (exact)
#define WCONV_BLKS (NQUAD / 256)            // 2304 (exact)
#define Q13 (P13 / 4)                       // 196608 quads per w1/w3 matrix

// Fused prep: blocks [0, WCONV_BLKS) do VECTORIZED weight convert (4 uints =
// 8 floats per thread — round 9 showed the 1-uint/thread version was latency-
// bound: 1 outstanding 8B load/lane, VALUBusy 30%, HBM 8.5%, 53 us);
// blocks [WCONV_BLKS, +N_TOK/4) do the router (+ xb = bf16(x)).
__global__ __launch_bounds__(256) void prep_kernel(
    const float* __restrict__ w1, const float* __restrict__ w3, const float* __restrict__ w2,
    unsigned short* __restrict__ w1b, unsigned short* __restrict__ w3b,
    unsigned short* __restrict__ w2b,
    const float* __restrict__ x, const float* __restrict__ rw,
    unsigned short* __restrict__ xb, int* __restrict__ as_e, float* __restrict__ as_gate) {
    __shared__ float rws[E_NUM * C_DIM];
    int tid = threadIdx.x;
    if (blockIdx.x < WCONV_BLKS) {
        int q = blockIdx.x * 256 + tid;  // quad index (4 uints = 8 bf16)
        if (q < 2 * Q13) {
            // w1/w3: [E][682][256] f32 -> [E][768][256] bf16, zero pad rows.
            const float* src = (q < Q13) ? w1 : w3;
            unsigned short* dst = (q < Q13) ? w1b : w3b;
            int i4 = (q < Q13) ? q : q - Q13;
            int e = i4 / (H_PAD * 32);              // 32 quads per 256-col row
            int rem = i4 - e * (H_PAD * 32);
            int r = rem >> 5;
            int qc = rem & 31;                      // quad-in-row -> float col qc*8
            int4 v = {0, 0, 0, 0};
            if (r < H_DIM) {
                const float* s = src + ((size_t)e * H_DIM + r) * C_DIM + qc * 8;  // 32B-aligned
                float4 f0 = *(const float4*)s;
                float4 f1 = *(const float4*)(s + 4);
                v.x = pk2(f0.x, f0.y); v.y = pk2(f0.z, f0.w);
                v.z = pk2(f1.x, f1.y); v.w = pk2(f1.z, f1.w);
            }
            *(int4*)((uint*)dst + (size_t)i4 * 4) = v;
        } else {
            // w2: [E][256][682] f32 -> [E][256][768] bf16, zero pad cols.
            // 682-float rows are only 8B-aligned -> float2 loads.
            int i4 = q - 2 * Q13;                   // quad into w2b
            int e = i4 / (C_DIM * 96);              // 96 quads per 768-col row
            int rem = i4 - e * (C_DIM * 96);
            int r = rem / 96;
            int qc = rem - r * 96;                  // uint cols [qc*4, qc*4+4)
            const float* s = w2 + ((size_t)e * C_DIM + r) * H_DIM;
            int4 v = {0, 0, 0, 0};
            int j0 = qc * 4;                        // valid uint cols: j < 341
#pragma unroll
            for (int k = 0; k < 4; k++) {
                int j = j0 + k;
                if (j * 2 < H_DIM) {
                    float2 f = *(const float2*)(s + j * 2);
                    ((uint*)&v)[k] = pk2(f.x, f.y);
                }
            }
            *(int4*)((uint*)w2b + (size_t)i4 * 4) = v;
        }
        return;
    }
    // ---- router part ----
    for (int i = tid; i < E_NUM * C_DIM; i += 256) rws[i] = rw[i];
    __syncthreads();
    int wave = tid >> 6, lane = tid & 63;
    int t = (blockIdx.x - WCONV_BLKS) * 4 + wave;
    const float4 xv = *(const float4*)(x + (size_t)t * C_DIM + lane * 4);
    uint2 pk;
    pk.x = pk2(xv.x, xv.y);
    pk.y = pk2(xv.z, xv.w);
    *(uint2*)(xb + (size_t)t * C_DIM + lane * 4) = pk;
    float p[E_NUM];
#pragma unroll
    for (int e = 0; e < E_NUM; e++) {
        const float* wr = &rws[e * C_DIM + lane * 4];
        p[e] = xv.x * wr[0] + xv.y * wr[1] + xv.z * wr[2] + xv.w * wr[3];
    }
#pragma unroll
    for (int off = 32; off >= 1; off >>= 1) {
#pragma unroll
        for (int e = 0; e < E_NUM; e++) p[e] += __shfl_down(p[e], off, 64);
    }
    if (lane == 0) {
        float m = p[0];
#pragma unroll
        for (int e = 1; e < E_NUM; e++) m = fmaxf(m, p[e]);
        float s = 0.f, q[E_NUM];
#pragma unroll
        for (int e = 0; e < E_NUM; e++) { q[e] = expf(p[e] - m); s += q[e]; }
#pragma unroll
        for (int e = 0; e < E_NUM; e++) q[e] /= s;
        int e0 = 0;
#pragma unroll
        for (int e = 1; e < E_NUM; e++) if (q[e] > q[e0]) e0 = e;
        int e1 = (e0 == 0) ? 1 : 0;
#pragma unroll
        for (int e = 0; e < E_NUM; e++) {
            if (e != e0 && q[e] > q[e1]) e1 = e;
        }
        float g0 = q[e0], g1 = q[e1];
        float denom = g0 + g1 + 1e-9f;
        g0 /= denom; g1 /= denom;
        as_e[t * 2] = e0; as_gate[t * 2] = g0;
        as_e[t * 2 + 1] = e1; as_gate[t * 2 + 1] = g1;
    }
}

// Per-block expert histogram (LDS atomics), 64 blocks x 512 assignments.
__global__ __launch_bounds__(256) void hist_kernel(const int* __restrict__ as_e,
                                                   int* __restrict__ block_hist) {
    __shared__ int lh[E_NUM];
    int b = blockIdx.x, tid = threadIdx.x;
    if (tid < E_NUM) lh[tid] = 0;
    __syncthreads();
    for (int i = tid; i < APB; i += 256) atomicAdd(&lh[as_e[b * APB + i]], 1);
    __syncthreads();
    if (tid < E_NUM) block_hist[b * E_NUM + tid] = lh[tid];
}

// Scan: expert totals -> offsets[9]; per-(block,expert) base cursors; and the
// COMPACT TILE MAP tile_base[9] (cumsum of ceil(cnt_e/128)).
__global__ void scan2_kernel(const int* __restrict__ block_hist, int* __restrict__ offsets,
                             int* __restrict__ block_base, int* __restrict__ tile_base) {
    __shared__ int tot[E_NUM], off[E_NUM];
    int e = threadIdx.x;
    if (e < E_NUM) {
        int s = 0;
        for (int b = 0; b < HB; b++) s += block_hist[b * E_NUM + e];
        tot[e] = s;
    }
    __syncthreads();
    if (e == 0) {
        int acc = 0;
        for (int i = 0; i < E_NUM; i++) { off[i] = acc; offsets[i] = acc; acc += tot[i]; }
        offsets[E_NUM] = acc;
        int t = 0;
        tile_base[0] = 0;
        for (int i = 0; i < E_NUM; i++) { t += (tot[i] + 127) / 128; tile_base[i + 1] = t; }
    }
    __syncthreads();
    if (e < E_NUM) {
        int acc = off[e];
        for (int b = 0; b < HB; b++) { block_base[b * E_NUM + e] = acc; acc += block_hist[b * E_NUM + e]; }
    }
}

// Scatter: row_token (expert-sorted) + inverse map as_row[a] = row.
__global__ __launch_bounds__(256) void scatter_kernel(
    const int* __restrict__ as_e, const int* __restrict__ block_base,
    int* __restrict__ row_token, int* __restrict__ as_row) {
    __shared__ int cur[E_NUM];
    int b = blockIdx.x, tid = threadIdx.x;
    if (tid < E_NUM) cur[tid] = block_base[b * E_NUM + tid];
    __syncthreads();
    for (int i = tid; i < APB; i += 256) {
        int a = b * APB + i;
        int e = as_e[a];
        int p = atomicAdd(&cur[e], 1);
        row_token[p] = a >> 1;
        as_row[a] = p;
    }
}

// Map compact tile id -> expert. 7 scalar compares on tile_base[].
__device__ __forceinline__ int tile_to_expert(const int* __restrict__ tile_base, int bid) {
    int e = 0;
#pragma unroll
    for (int i = 1; i < E_NUM; i++) e += (bid >= tile_base[i]) ? 1 : 0;
    return e;
}

// ---------------- Pass 1: h = silu(x.w1^T) * (x.w3^T) ----------------
// BYTE-IDENTICAL to round-8 verified version (47.4 us, FETCH 34.5 MB).
// XCD-aware 1D grid: all 6 col-chunks of a row-tile on the SAME XCD (private
// L2) -> gathered A-tile L2-served for chunks 1..5 (FETCH 59->34.5 MB).
// launch_bounds stays (256,2) — (256,3) spills the accumulator (round 3).
__global__ __launch_bounds__(256, 2) void expert_ffn1(
    const unsigned short* __restrict__ xb, const unsigned short* __restrict__ w1b,
    const unsigned short* __restrict__ w3b, const int* __restrict__ offsets,
    const int* __restrict__ tile_base, const int* __restrict__ row_token,
    unsigned short* __restrict__ h) {
    int bid = blockIdx.x;            // 0..1583
    int xcd = bid & 7;
    int local = bid >> 3;            // 0..197
    int tq = local / 6;              // 0..32
    int c = local - tq * 6;          // 0..5
    int t = tq * 8 + xcd;            // tile id 0..263
    if (t >= tile_base[E_NUM]) return;
    int e = tile_to_expert(tile_base, t);
    int mt = t - tile_base[e];
    int off0 = offsets[e], off1 = offsets[e + 1];
    int row0 = off0 + mt * 128;
    int mval = min(128, off1 - row0);

    __shared__ union {
        unsigned short buf[2][12288];
        unsigned short Hs[128 * 136];  // 34816 B (overlaps buffers)
    } sm;

    int tid = threadIdx.x, lane = tid & 63, w = tid >> 6;
    int wm = w & 1, wn = w >> 1;
    int ra = tid >> 2;                              // staging row (round 0); +64 for round 1
    int acol = (((tid & 3) ^ ((ra >> 1) & 3))) * 8; // XOR-swizzled 16B source chunk
    int tok0 = row_token[row0 + min(ra, mval - 1)];
    int tok1 = row_token[row0 + min(ra + 64, mval - 1)];
    const unsigned short* a0p = xb + (size_t)tok0 * C_DIM + acol;
    const unsigned short* a1p = xb + (size_t)tok1 * C_DIM + acol;
    const unsigned short* b1p0 = w1b + ((size_t)e * H_PAD + c * 128 + ra) * C_DIM + acol;
    const unsigned short* b1p1 = b1p0 + (size_t)64 * C_DIM;
    const unsigned short* b3p0 = w3b + ((size_t)e * H_PAD + c * 128 + ra) * C_DIM + acol;
    const unsigned short* b3p1 = b3p0 + (size_t)64 * C_DIM;

    int wofs = w * 512;
    auto stage = [&](int kt, unsigned short* base) {
        int kb = kt * 32;
        load_lds16(a0p + kb, base + wofs);
        load_lds16(a1p + kb, base + 2048 + wofs);
        load_lds16(b1p0 + kb, base + 4096 + wofs);
        load_lds16(b1p1 + kb, base + 6144 + wofs);
        load_lds16(b3p0 + kb, base + 8192 + wofs);
        load_lds16(b3p1 + kb, base + 10240 + wofs);
    };

    int ko = ((lane >> 4) ^ ((lane >> 1) & 3)) * 8;
    int l15 = lane & 15;
    int arowf = wm * 64 + l15;
    int browf = wn * 64 + l15;
    int quad = lane >> 4;

    stage(0, sm.buf[0]);

    floatx4 acc1[4][4], acc3[4][4];
#pragma unroll
    for (int m = 0; m < 4; m++)
#pragma unroll
        for (int n = 0; n < 4; n++) {
            acc1[m][n] = (floatx4){0.f, 0.f, 0.f, 0.f};
            acc3[m][n] = (floatx4){0.f, 0.f, 0.f, 0.f};
        }

#pragma unroll
    for (int kt = 0; kt < 8; kt++) {
        if (kt + 1 < 8) stage(kt + 1, sm.buf[(kt + 1) & 1]);
        if (kt + 1 < 8) { VMCNT6; } else { VMCNT0; }
        __builtin_amdgcn_s_barrier();
        const unsigned short* cur = sm.buf[kt & 1];
        short8 af[4], b1f[4], b3f[4];
#pragma unroll
        for (int m = 0; m < 4; m++) af[m] = *(short8*)&cur[(arowf + m * 16) * 32 + ko];
#pragma unroll
        for (int n = 0; n < 4; n++) {
            b1f[n] = *(short8*)&cur[4096 + (browf + n * 16) * 32 + ko];
            b3f[n] = *(short8*)&cur[8192 + (browf + n * 16) * 32 + ko];
        }
        __builtin_amdgcn_s_setprio(1);
#pragma unroll
        for (int m = 0; m < 4; m++)
#pragma unroll
            for (int n = 0; n < 4; n++) {
                acc1[m][n] = __builtin_amdgcn_mfma_f32_16x16x32_bf16(af[m], b1f[n], acc1[m][n], 0, 0, 0);
                acc3[m][n] = __builtin_amdgcn_mfma_f32_16x16x32_bf16(af[m], b3f[n], acc3[m][n], 0, 0, 0);
            }
        __builtin_amdgcn_s_setprio(0);
        LGKM0;
        __builtin_amdgcn_s_barrier();
    }
    __syncthreads();

    // Epilogue: silu(h1)*h3 -> Hs (bf16) -> coalesced 16B stores
#pragma unroll
    for (int m = 0; m < 4; m++)
#pragma unroll
        for (int n = 0; n < 4; n++)
#pragma unroll
            for (int r = 0; r < 4; r++) {
                float h1 = acc1[m][n][r], h3 = acc3[m][n][r];
                float sv = h1 / (1.0f + __expf(-h1)) * h3;
                sm.Hs[(wm * 64 + m * 16 + quad * 4 + r) * 136 + wn * 64 + n * 16 + l15] = f2bf(sv);
            }
    __syncthreads();
#pragma unroll
    for (int it = 0; it < 8; it++) {
        int s = it * 256 + tid;
        int row = s >> 4, c16 = s & 15;
        if (row < mval)
            *(int4*)(h + (size_t)(row0 + row) * H_PAD + c * 128 + c16 * 8) =
                *(int4*)&sm.Hs[row * 136 + c16 * 8];
    }
}

// ---------------- Pass 2: y = h . w2^T (bf16 y, no atomics) ----------------
// BYTE-IDENTICAL to round-8 verified version. Same XCD-aware mapping: both
// C-chunks of a row-tile on one XCD (L2-shares the 192 KB h-row panel).
// BK=64, 2-deep 64 KB LDS, counted vmcnt(8). launch_bounds (256,2).
__global__ __launch_bounds__(256, 2) void expert_ffn2(
    const unsigned short* __restrict__ h, const unsigned short* __restrict__ w2b,
    const int* __restrict__ offsets, const int* __restrict__ tile_base,
    unsigned short* __restrict__ y) {
    int bid = blockIdx.x;            // 0..527
    int xcd = bid & 7;
    int local = bid >> 3;            // 0..65
    int tq = local >> 1;             // 0..32
    int p = local & 1;               // C chunk
    int t = tq * 8 + xcd;            // tile id 0..263
    if (t >= tile_base[E_NUM]) return;
    int e = tile_to_expert(tile_base, t);
    int mt = t - tile_base[e];
    int off0 = offsets[e], off1 = offsets[e + 1];
    int row0 = off0 + mt * 128;
    int mval = min(128, off1 - row0);

    __shared__ union {
        unsigned short buf[2][16384];
        unsigned short Hs[128 * 136];  // 34816 B
    } sm;

    int tid = threadIdx.x, lane = tid & 63, w = tid >> 6;
    int wm = w & 1, wn = w >> 1;
    int ra = tid >> 2;
    int acol = (((tid & 3) ^ ((ra >> 1) & 3))) * 8;  // XOR-swizzled source chunk
    const unsigned short* ap0 = h + (size_t)(row0 + ra) * H_PAD + acol;
    const unsigned short* ap1 = ap0 + (size_t)64 * H_PAD;
    const unsigned short* bp0 = w2b + ((size_t)e * C_DIM + p * 128 + ra) * H_PAD + acol;
    const unsigned short* bp1 = bp0 + (size_t)64 * H_PAD;

    int wofs = w * 512;
    auto stage = [&](int kt, unsigned short* base) {  // kt in 64-col tiles
        int kb = kt * 64;
#pragma unroll
        for (int kk = 0; kk < 2; kk++) {
            int ks = kb + kk * 32;
            unsigned short* b2 = base + kk * 8192;
            load_lds16(ap0 + ks, b2 + wofs);
            load_lds16(ap1 + ks, b2 + 2048 + wofs);
            load_lds16(bp0 + ks, b2 + 4096 + wofs);
            load_lds16(bp1 + ks, b2 + 6144 + wofs);
        }
    };

    int ko = ((lane >> 4) ^ ((lane >> 1) & 3)) * 8;
    int l15 = lane & 15;
    int arowf = wm * 64 + l15;
    int browf = wn * 64 + l15;
    int quad = lane >> 4;

    stage(0, sm.buf[0]);

    floatx4 acc[4][4];
#pragma unroll
    for (int m = 0; m < 4; m++)
#pragma unroll
        for (int n = 0; n < 4; n++) acc[m][n] = (floatx4){0.f, 0.f, 0.f, 0.f};

#pragma unroll
    for (int kt = 0; kt < H_PAD / 64; kt++) {  // 12
        if (kt + 1 < H_PAD / 64) stage(kt + 1, sm.buf[(kt + 1) & 1]);
        if (kt + 1 < H_PAD / 64) { VMCNT8; } else { VMCNT0; }
        __builtin_amdgcn_s_barrier();
        const unsigned short* cur = sm.buf[kt & 1];
#pragma unroll
        for (int kk = 0; kk < 2; kk++) {
            const unsigned short* c2 = cur + kk * 8192;
            short8 af[4], bf[4];
#pragma unroll
            for (int m = 0; m < 4; m++) af[m] = *(short8*)&c2[(arowf + m * 16) * 32 + ko];
#pragma unroll
            for (int n = 0; n < 4; n++) bf[n] = *(short8*)&c2[4096 + (browf + n * 16) * 32 + ko];
            __builtin_amdgcn_s_setprio(1);
#pragma unroll
            for (int m = 0; m < 4; m++)
#pragma unroll
                for (int n = 0; n < 4; n++)
                    acc[m][n] = __builtin_amdgcn_mfma_f32_16x16x32_bf16(af[m], bf[n], acc[m][n], 0, 0, 0);
            __builtin_amdgcn_s_setprio(0);
        }
        LGKM0;
        __builtin_amdgcn_s_barrier();
    }
    __syncthreads();

    // Epilogue: y chunk (bf16) via Hs transpose
#pragma unroll
    for (int m = 0; m < 4; m++)
#pragma unroll
        for (int n = 0; n < 4; n++)
#pragma unroll
            for (int r = 0; r < 4; r++)
                sm.Hs[(wm * 64 + m * 16 + quad * 4 + r) * 136 + wn * 64 + n * 16 + l15] =
                    f2bf(acc[m][n][r]);
    __syncthreads();
#pragma unroll
    for (int it = 0; it < 8; it++) {
        int s = it * 256 + tid;
        int row = s >> 4, c16 = s & 15;
        if (row < mval)
            *(int4*)(y + (size_t)(row0 + row) * C_DIM + p * 128 + c16 * 8) =
                *(int4*)&sm.Hs[row * 136 + c16 * 8];
    }
}

// Combine: out[t][:] = g0*y[row(2t)][:] + g1*y[row(2t+1)][:]  (fp32 out)
__global__ __launch_bounds__(256) void combine_kernel(
    const unsigned short* __restrict__ y, const int* __restrict__ as_row,
    const float* __restrict__ as_gate, float* __restrict__ out) {
    int tid = threadIdx.x, lane = tid & 63;
    int t = blockIdx.x * 4 + (tid >> 6);
    int r0 = as_row[2 * t], r1 = as_row[2 * t + 1];
    float g0 = as_gate[2 * t], g1 = as_gate[2 * t + 1];
    uint2 a = *(const uint2*)(y + (size_t)r0 * C_DIM + lane * 4);
    uint2 b = *(const uint2*)(y + (size_t)r1 * C_DIM + lane * 4);
    float4 o;
    o.x = g0 * bf2f((unsigned short)(a.x & 0xffff)) + g1 * bf2f((unsigned short)(b.x & 0xffff));
    o.y = g0 * bf2f((unsigned short)(a.x >> 16)) + g1 * bf2f((unsigned short)(b.x >> 16));
    o.z = g0 * bf2f((unsigned short)(a.y & 0xffff)) + g1 * bf2f((unsigned short)(b.y & 0xffff));
    o.w = g0 * bf2f((unsigned short)(a.y >> 16)) + g1 * bf2f((unsigned short)(b.y >> 16));
    *(float4*)(out + (size_t)t * C_DIM + lane * 4) = o;
}

extern "C" void kernel_launch(void* const* d_in, const int* in_sizes, int n_in,
                              void* d_out, int out_size, void* d_ws, size_t ws_size,
                              hipStream_t stream) {
    const float* x = (const float*)d_in[0];
    const float* rw = (const float*)d_in[1];
    const float* w1 = (const float*)d_in[2];
    const float* w2 = (const float*)d_in[3];
    const float* w3 = (const float*)d_in[4];
    float* out = (float*)d_out;

    char* ws = (char*)d_ws;
    size_t o = 0;
    auto alloc = [&](size_t bytes) {
        void* p = ws + o;
        o = (o + bytes + 255) & ~(size_t)255;
        return p;
    };
    unsigned short* xb = (unsigned short*)alloc((size_t)N_TOK * C_DIM * 2);
    unsigned short* w1b = (unsigned short*)alloc((size_t)E_NUM * H_PAD * C_DIM * 2);
    unsigned short* w3b = (unsigned short*)alloc((size_t)E_NUM * H_PAD * C_DIM * 2);
    unsigned short* w2b = (unsigned short*)alloc((size_t)E_NUM * C_DIM * H_PAD * 2);
    unsigned short* hbuf = (unsigned short*)alloc((size_t)(NROWS + 128) * H_PAD * 2);
    unsigned short* ybuf = (unsigned short*)alloc((size_t)NROWS * C_DIM * 2);
    int* offsets = (int*)alloc((E_NUM + 1) * 4);
    int* tile_base = (int*)alloc((E_NUM + 1) * 4);
    int* as_e = (int*)alloc(NROWS * 4);
    float* as_gate = (float*)alloc(NROWS * 4);
    int* row_token = (int*)alloc(NROWS * 4);
    int* as_row = (int*)alloc(NROWS * 4);
    int* block_hist = (int*)alloc(HB * E_NUM * 4);
    int* block_base = (int*)alloc(HB * E_NUM * 4);

    prep_kernel<<<WCONV_BLKS + N_TOK / 4, 256, 0, stream>>>(
        w1, w3, w2, w1b, w3b, w2b, x, rw, xb, as_e, as_gate);
    hist_kernel<<<HB, 256, 0, stream>>>(as_e, block_hist);
    scan2_kernel<<<1, 64, 0, stream>>>(block_hist, offsets, block_base, tile_base);
    scatter_kernel<<<HB, 256, 0, stream>>>(as_e, block_base, row_token, as_row);

    expert_ffn1<<<6 * MAXTILE, 256, 0, stream>>>(xb, w1b, w3b, offsets, tile_base,
                                                 row_token, hbuf);
    expert_ffn2<<<2 * MAXTILE, 256, 0, stream>>>(hbuf, w2b, offsets, tile_base, ybuf);
    combine_kernel<<<N_TOK / 4, 256, 0, stream>>>(ybuf, as_row, as_gate, out);
}

// Round 11
// 173.417 us; speedup vs baseline: 1.1808x; 1.0324x over previous
//
#include <hip/hip_runtime.h>
#include <hip/hip_bf16.h>

#define N_TOK 16384
#define C_DIM 256
#define E_NUM 8
#define H_DIM 682
#define H_PAD 768          // 6 * 128 (pad rows/cols are exact zeros)
#define NROWS (N_TOK * 2)  // total expert-assignments (top-2)
#define HB 64              // histogram/scatter blocks
#define APB (NROWS / HB)   // assignments per block = 512
#define MAXTILE 264        // sum ceil(cnt_e/128) <= 32768/128 + 8 = 264 (= 8*33)

typedef short short8 __attribute__((ext_vector_type(8)));
typedef float floatx4 __attribute__((ext_vector_type(4)));
typedef unsigned int uint;

__device__ inline unsigned short f2bf(float v) {
    union { float f; uint u; } x; x.f = v;
    uint r = (x.u + 0x7fffu + ((x.u >> 16) & 1u)) >> 16;
    return (unsigned short)r;
}
__device__ inline float bf2f(unsigned short v) {
    union { uint u; float f; } x; x.u = ((uint)v) << 16; return x.f;
}
__device__ inline uint pk2(float a, float b) {
    return (uint)f2bf(a) | ((uint)f2bf(b) << 16);
}

// Async global->LDS 16B/lane. LDS dst: wave-uniform base + lane*16.
__device__ __forceinline__ void load_lds16(const void* g, void* l) {
    __builtin_amdgcn_global_load_lds(
        (const __attribute__((address_space(1))) unsigned int*)g,
        (__attribute__((address_space(3))) unsigned int*)l, 16, 0, 0);
}

// Counted vmcnt waits: wait for current stage, leave next stage in flight.
#define VMCNT8 asm volatile("s_waitcnt vmcnt(8)" ::: "memory")
#define VMCNT6 asm volatile("s_waitcnt vmcnt(6)" ::: "memory")
#define VMCNT0 asm volatile("s_waitcnt vmcnt(0)" ::: "memory")
#define LGKM0  asm volatile("s_waitcnt lgkmcnt(0)" ::: "memory")

#define P13 (E_NUM * H_PAD * (C_DIM / 2))   // 786432 uints per w1b/w3b
#define P2  (E_NUM * C_DIM * (H_PAD / 2))   // 786432 uints for w2b
#define NQUAD ((2 * P13 + P2) / 4)          // 589824 quad-groups (exact)
#define WCONV_BLKS (NQUAD / 256)            // 2304 (exact)
#define Q13 (P13 / 4)                       // 196608 quads per w1/w3 matrix

// Fused prep: blocks [0, WCONV_BLKS) do VECTORIZED weight convert (4 uints =
// 8 floats per thread); blocks [WCONV_BLKS, +N_TOK/4) do the router
// (+ xb = bf16(x)).
__global__ __launch_bounds__(256) void prep_kernel(
    const float* __restrict__ w1, const float* __restrict__ w3, const float* __restrict__ w2,
    unsigned short* __restrict__ w1b, unsigned short* __restrict__ w3b,
    unsigned short* __restrict__ w2b,
    const float* __restrict__ x, const float* __restrict__ rw,
    unsigned short* __restrict__ xb, int* __restrict__ as_e, float* __restrict__ as_gate) {
    __shared__ float rws[E_NUM * C_DIM];
    int tid = threadIdx.x;
    if (blockIdx.x < WCONV_BLKS) {
        int q = blockIdx.x * 256 + tid;  // quad index (4 uints = 8 bf16)
        if (q < 2 * Q13) {
            // w1/w3: [E][682][256] f32 -> [E][768][256] bf16, zero pad rows.
            const float* src = (q < Q13) ? w1 : w3;
            unsigned short* dst = (q < Q13) ? w1b : w3b;
            int i4 = (q < Q13) ? q : q - Q13;
            int e = i4 / (H_PAD * 32);              // 32 quads per 256-col row
            int rem = i4 - e * (H_PAD * 32);
            int r = rem >> 5;
            int qc = rem & 31;                      // quad-in-row -> float col qc*8
            int4 v = {0, 0, 0, 0};
            if (r < H_DIM) {
                const float* s = src + ((size_t)e * H_DIM + r) * C_DIM + qc * 8;  // 32B-aligned
                float4 f0 = *(const float4*)s;
                float4 f1 = *(const float4*)(s + 4);
                v.x = pk2(f0.x, f0.y); v.y = pk2(f0.z, f0.w);
                v.z = pk2(f1.x, f1.y); v.w = pk2(f1.z, f1.w);
            }
            *(int4*)((uint*)dst + (size_t)i4 * 4) = v;
        } else {
            // w2: [E][256][682] f32 -> [E][256][768] bf16, zero pad cols.
            // 682-float rows are only 8B-aligned -> float2 loads.
            int i4 = q - 2 * Q13;                   // quad into w2b
            int e = i4 / (C_DIM * 96);              // 96 quads per 768-col row
            int rem = i4 - e * (C_DIM * 96);
            int r = rem / 96;
            int qc = rem - r * 96;                  // uint cols [qc*4, qc*4+4)
            const float* s = w2 + ((size_t)e * C_DIM + r) * H_DIM;
            int4 v = {0, 0, 0, 0};
            int j0 = qc * 4;                        // valid uint cols: j < 341
#pragma unroll
            for (int k = 0; k < 4; k++) {
                int j = j0 + k;
                if (j * 2 < H_DIM) {
                    float2 f = *(const float2*)(s + j * 2);
                    ((uint*)&v)[k] = pk2(f.x, f.y);
                }
            }
            *(int4*)((uint*)w2b + (size_t)i4 * 4) = v;
        }
        return;
    }
    // ---- router part ----
    for (int i = tid; i < E_NUM * C_DIM; i += 256) rws[i] = rw[i];
    __syncthreads();
    int wave = tid >> 6, lane = tid & 63;
    int t = (blockIdx.x - WCONV_BLKS) * 4 + wave;
    const float4 xv = *(const float4*)(x + (size_t)t * C_DIM + lane * 4);
    uint2 pk;
    pk.x = pk2(xv.x, xv.y);
    pk.y = pk2(xv.z, xv.w);
    *(uint2*)(xb + (size_t)t * C_DIM + lane * 4) = pk;
    float p[E_NUM];
#pragma unroll
    for (int e = 0; e < E_NUM; e++) {
        const float* wr = &rws[e * C_DIM + lane * 4];
        p[e] = xv.x * wr[0] + xv.y * wr[1] + xv.z * wr[2] + xv.w * wr[3];
    }
#pragma unroll
    for (int off = 32; off >= 1; off >>= 1) {
#pragma unroll
        for (int e = 0; e < E_NUM; e++) p[e] += __shfl_down(p[e], off, 64);
    }
    if (lane == 0) {
        float m = p[0];
#pragma unroll
        for (int e = 1; e < E_NUM; e++) m = fmaxf(m, p[e]);
        float s = 0.f, q[E_NUM];
#pragma unroll
        for (int e = 0; e < E_NUM; e++) { q[e] = expf(p[e] - m); s += q[e]; }
#pragma unroll
        for (int e = 0; e < E_NUM; e++) q[e] /= s;
        int e0 = 0;
#pragma unroll
        for (int e = 1; e < E_NUM; e++) if (q[e] > q[e0]) e0 = e;
        int e1 = (e0 == 0) ? 1 : 0;
#pragma unroll
        for (int e = 0; e < E_NUM; e++) {
            if (e != e0 && q[e] > q[e1]) e1 = e;
        }
        float g0 = q[e0], g1 = q[e1];
        float denom = g0 + g1 + 1e-9f;
        g0 /= denom; g1 /= denom;
        as_e[t * 2] = e0; as_gate[t * 2] = g0;
        as_e[t * 2 + 1] = e1; as_gate[t * 2 + 1] = g1;
    }
}

// Per-block expert histogram (LDS atomics), 64 blocks x 512 assignments.
__global__ __launch_bounds__(256) void hist_kernel(const int* __restrict__ as_e,
                                                   int* __restrict__ block_hist) {
    __shared__ int lh[E_NUM];
    int b = blockIdx.x, tid = threadIdx.x;
    if (tid < E_NUM) lh[tid] = 0;
    __syncthreads();
    for (int i = tid; i < APB; i += 256) atomicAdd(&lh[as_e[b * APB + i]], 1);
    __syncthreads();
    if (tid < E_NUM) block_hist[b * E_NUM + tid] = lh[tid];
}

// Scan: expert totals -> offsets[9]; per-(block,expert) base cursors; and the
// COMPACT TILE MAP tile_base[9] (cumsum of ceil(cnt_e/128)).
__global__ void scan2_kernel(const int* __restrict__ block_hist, int* __restrict__ offsets,
                             int* __restrict__ block_base, int* __restrict__ tile_base) {
    __shared__ int tot[E_NUM], off[E_NUM];
    int e = threadIdx.x;
    if (e < E_NUM) {
        int s = 0;
        for (int b = 0; b < HB; b++) s += block_hist[b * E_NUM + e];
        tot[e] = s;
    }
    __syncthreads();
    if (e == 0) {
        int acc = 0;
        for (int i = 0; i < E_NUM; i++) { off[i] = acc; offsets[i] = acc; acc += tot[i]; }
        offsets[E_NUM] = acc;
        int t = 0;
        tile_base[0] = 0;
        for (int i = 0; i < E_NUM; i++) { t += (tot[i] + 127) / 128; tile_base[i + 1] = t; }
    }
    __syncthreads();
    if (e < E_NUM) {
        int acc = off[e];
        for (int b = 0; b < HB; b++) { block_base[b * E_NUM + e] = acc; acc += block_hist[b * E_NUM + e]; }
    }
}

// Scatter: row_token (expert-sorted) + inverse map as_row[a] = row.
__global__ __launch_bounds__(256) void scatter_kernel(
    const int* __restrict__ as_e, const int* __restrict__ block_base,
    int* __restrict__ row_token, int* __restrict__ as_row) {
    __shared__ int cur[E_NUM];
    int b = blockIdx.x, tid = threadIdx.x;
    if (tid < E_NUM) cur[tid] = block_base[b * E_NUM + tid];
    __syncthreads();
    for (int i = tid; i < APB; i += 256) {
        int a = b * APB + i;
        int e = as_e[a];
        int p = atomicAdd(&cur[e], 1);
        row_token[p] = a >> 1;
        as_row[a] = p;
    }
}

// Map compact tile id -> expert. 7 scalar compares on tile_base[].
__device__ __forceinline__ int tile_to_expert(const int* __restrict__ tile_base, int bid) {
    int e = 0;
#pragma unroll
    for (int i = 1; i < E_NUM; i++) e += (bid >= tile_base[i]) ? 1 : 0;
    return e;
}

// ---------------- Pass 1: h = silu(x.w1^T) * (x.w3^T) ----------------
// PHASE-SPLIT K-loop (T3 port): ffn1 was pinned at 557 TF = the 2-barrier-per-
// K-step structural ceiling (m233); five schedule micro-edits were null. Now:
// 3-deep buffers (72 KB, 2 blocks/CU), counted vmcnt(6) at top of iter, then
//   phase A: read af+b1f, issue 3 loads of stage(kt+2), read b3f,
//            setprio + 16 MFMA acc1;  barrier;
//   phase B: issue remaining 3 loads, setprio + 16 MFMA acc3;  barrier.
// Rotation hazard audited: stage(kt+2) targets buf[(kt-1)%3] whose ds_reads
// were consumed by MFMAs before the iter-kt top barrier.
// XCD-aware 1D grid unchanged (FETCH 34.5 MB). launch_bounds (256,2) — (256,3)
// spills the accumulator (round 3).
__global__ __launch_bounds__(256, 2) void expert_ffn1(
    const unsigned short* __restrict__ xb, const unsigned short* __restrict__ w1b,
    const unsigned short* __restrict__ w3b, const int* __restrict__ offsets,
    const int* __restrict__ tile_base, const int* __restrict__ row_token,
    unsigned short* __restrict__ h) {
    int bid = blockIdx.x;            // 0..1583
    int xcd = bid & 7;
    int local = bid >> 3;            // 0..197
    int tq = local / 6;              // 0..32
    int c = local - tq * 6;          // 0..5
    int t = tq * 8 + xcd;            // tile id 0..263
    if (t >= tile_base[E_NUM]) return;
    int e = tile_to_expert(tile_base, t);
    int mt = t - tile_base[e];
    int off0 = offsets[e], off1 = offsets[e + 1];
    int row0 = off0 + mt * 128;
    int mval = min(128, off1 - row0);

    __shared__ union {
        unsigned short buf[3][12288];  // 73728 B (3-deep for phase-split)
        unsigned short Hs[128 * 136];  // 34816 B (overlaps buffers)
    } sm;

    int tid = threadIdx.x, lane = tid & 63, w = tid >> 6;
    int wm = w & 1, wn = w >> 1;
    int ra = tid >> 2;                              // staging row (round 0); +64 for round 1
    int acol = (((tid & 3) ^ ((ra >> 1) & 3))) * 8; // XOR-swizzled 16B source chunk
    int tok0 = row_token[row0 + min(ra, mval - 1)];
    int tok1 = row_token[row0 + min(ra + 64, mval - 1)];
    const unsigned short* a0p = xb + (size_t)tok0 * C_DIM + acol;
    const unsigned short* a1p = xb + (size_t)tok1 * C_DIM + acol;
    const unsigned short* b1p0 = w1b + ((size_t)e * H_PAD + c * 128 + ra) * C_DIM + acol;
    const unsigned short* b1p1 = b1p0 + (size_t)64 * C_DIM;
    const unsigned short* b3p0 = w3b + ((size_t)e * H_PAD + c * 128 + ra) * C_DIM + acol;
    const unsigned short* b3p1 = b3p0 + (size_t)64 * C_DIM;

    int wofs = w * 512;
    auto stageA = [&](int kt, unsigned short* base) {  // first half: A + B1-lo
        int kb = kt * 32;
        load_lds16(a0p + kb, base + wofs);
        load_lds16(a1p + kb, base + 2048 + wofs);
        load_lds16(b1p0 + kb, base + 4096 + wofs);
    };
    auto stageB = [&](int kt, unsigned short* base) {  // second half: B1-hi + B3
        int kb = kt * 32;
        load_lds16(b1p1 + kb, base + 6144 + wofs);
        load_lds16(b3p0 + kb, base + 8192 + wofs);
        load_lds16(b3p1 + kb, base + 10240 + wofs);
    };

    int ko = ((lane >> 4) ^ ((lane >> 1) & 3)) * 8;
    int l15 = lane & 15;
    int arowf = wm * 64 + l15;
    int browf = wn * 64 + l15;
    int quad = lane >> 4;

    stageA(0, sm.buf[0]); stageB(0, sm.buf[0]);
    stageA(1, sm.buf[1]); stageB(1, sm.buf[1]);

    floatx4 acc1[4][4], acc3[4][4];
#pragma unroll
    for (int m = 0; m < 4; m++)
#pragma unroll
        for (int n = 0; n < 4; n++) {
            acc1[m][n] = (floatx4){0.f, 0.f, 0.f, 0.f};
            acc3[m][n] = (floatx4){0.f, 0.f, 0.f, 0.f};
        }

#pragma unroll
    for (int kt = 0; kt < 8; kt++) {
        // stage(kt) landed; stage(kt+1)'s 6 loads stay in flight.
        if (kt < 7) { VMCNT6; } else { VMCNT0; }
        __builtin_amdgcn_s_barrier();
        const unsigned short* cur = sm.buf[kt % 3];
        unsigned short* nbuf = sm.buf[(kt + 2) % 3];
        // ---- phase A ----
        short8 af[4], b1f[4], b3f[4];
#pragma unroll
        for (int m = 0; m < 4; m++) af[m] = *(short8*)&cur[(arowf + m * 16) * 32 + ko];
#pragma unroll
        for (int n = 0; n < 4; n++) b1f[n] = *(short8*)&cur[4096 + (browf + n * 16) * 32 + ko];
        if (kt + 2 < 8) stageA(kt + 2, nbuf);
#pragma unroll
        for (int n = 0; n < 4; n++) b3f[n] = *(short8*)&cur[8192 + (browf + n * 16) * 32 + ko];
        __builtin_amdgcn_s_setprio(1);
#pragma unroll
        for (int m = 0; m < 4; m++)
#pragma unroll
            for (int n = 0; n < 4; n++)
                acc1[m][n] = __builtin_amdgcn_mfma_f32_16x16x32_bf16(af[m], b1f[n], acc1[m][n], 0, 0, 0);
        __builtin_amdgcn_s_setprio(0);
        __builtin_amdgcn_s_barrier();
        // ---- phase B ----
        if (kt + 2 < 8) stageB(kt + 2, nbuf);
        __builtin_amdgcn_s_setprio(1);
#pragma unroll
        for (int m = 0; m < 4; m++)
#pragma unroll
            for (int n = 0; n < 4; n++)
                acc3[m][n] = __builtin_amdgcn_mfma_f32_16x16x32_bf16(af[m], b3f[n], acc3[m][n], 0, 0, 0);
        __builtin_amdgcn_s_setprio(0);
        __builtin_amdgcn_s_barrier();
    }
    __syncthreads();  // all compute done before Hs overwrites buffers

    // Epilogue: silu(h1)*h3 -> Hs (bf16) -> coalesced 16B stores
#pragma unroll
    for (int m = 0; m < 4; m++)
#pragma unroll
        for (int n = 0; n < 4; n++)
#pragma unroll
            for (int r = 0; r < 4; r++) {
                float h1 = acc1[m][n][r], h3 = acc3[m][n][r];
                float sv = h1 / (1.0f + __expf(-h1)) * h3;
                sm.Hs[(wm * 64 + m * 16 + quad * 4 + r) * 136 + wn * 64 + n * 16 + l15] = f2bf(sv);
            }
    __syncthreads();
#pragma unroll
    for (int it = 0; it < 8; it++) {
        int s = it * 256 + tid;
        int row = s >> 4, c16 = s & 15;
        if (row < mval)
            *(int4*)(h + (size_t)(row0 + row) * H_PAD + c * 128 + c16 * 8) =
                *(int4*)&sm.Hs[row * 136 + c16 * 8];
    }
}

// ---------------- Pass 2: y = h . w2^T (bf16 y, no atomics) ----------------
// BYTE-IDENTICAL to round-8 verified version. XCD-aware mapping: both
// C-chunks of a row-tile on one XCD (L2-shares the 192 KB h-row panel).
// BK=64, 2-deep 64 KB LDS, counted vmcnt(8). launch_bounds (256,2).
__global__ __launch_bounds__(256, 2) void expert_ffn2(
    const unsigned short* __restrict__ h, const unsigned short* __restrict__ w2b,
    const int* __restrict__ offsets, const int* __restrict__ tile_base,
    unsigned short* __restrict__ y) {
    int bid = blockIdx.x;            // 0..527
    int xcd = bid & 7;
    int local = bid >> 3;            // 0..65
    int tq = local >> 1;             // 0..32
    int p = local & 1;               // C chunk
    int t = tq * 8 + xcd;            // tile id 0..263
    if (t >= tile_base[E_NUM]) return;
    int e = tile_to_expert(tile_base, t);
    int mt = t - tile_base[e];
    int off0 = offsets[e], off1 = offsets[e + 1];
    int row0 = off0 + mt * 128;
    int mval = min(128, off1 - row0);

    __shared__ union {
        unsigned short buf[2][16384];
        unsigned short Hs[128 * 136];  // 34816 B
    } sm;

    int tid = threadIdx.x, lane = tid & 63, w = tid >> 6;
    int wm = w & 1, wn = w >> 1;
    int ra = tid >> 2;
    int acol = (((tid & 3) ^ ((ra >> 1) & 3))) * 8;  // XOR-swizzled source chunk
    const unsigned short* ap0 = h + (size_t)(row0 + ra) * H_PAD + acol;
    const unsigned short* ap1 = ap0 + (size_t)64 * H_PAD;
    const unsigned short* bp0 = w2b + ((size_t)e * C_DIM + p * 128 + ra) * H_PAD + acol;
    const unsigned short* bp1 = bp0 + (size_t)64 * H_PAD;

    int wofs = w * 512;
    auto stage = [&](int kt, unsigned short* base) {  // kt in 64-col tiles
        int kb = kt * 64;
#pragma unroll
        for (int kk = 0; kk < 2; kk++) {
            int ks = kb + kk * 32;
            unsigned short* b2 = base + kk * 8192;
            load_lds16(ap0 + ks, b2 + wofs);
            load_lds16(ap1 + ks, b2 + 2048 + wofs);
            load_lds16(bp0 + ks, b2 + 4096 + wofs);
            load_lds16(bp1 + ks, b2 + 6144 + wofs);
        }
    };

    int ko = ((lane >> 4) ^ ((lane >> 1) & 3)) * 8;
    int l15 = lane & 15;
    int arowf = wm * 64 + l15;
    int browf = wn * 64 + l15;
    int quad = lane >> 4;

    stage(0, sm.buf[0]);

    floatx4 acc[4][4];
#pragma unroll
    for (int m = 0; m < 4; m++)
#pragma unroll
        for (int n = 0; n < 4; n++) acc[m][n] = (floatx4){0.f, 0.f, 0.f, 0.f};

#pragma unroll
    for (int kt = 0; kt < H_PAD / 64; kt++) {  // 12
        if (kt + 1 < H_PAD / 64) stage(kt + 1, sm.buf[(kt + 1) & 1]);
        if (kt + 1 < H_PAD / 64) { VMCNT8; } else { VMCNT0; }
        __builtin_amdgcn_s_barrier();
        const unsigned short* cur = sm.buf[kt & 1];
#pragma unroll
        for (int kk = 0; kk < 2; kk++) {
            const unsigned short* c2 = cur + kk * 8192;
            short8 af[4], bf[4];
#pragma unroll
            for (int m = 0; m < 4; m++) af[m] = *(short8*)&c2[(arowf + m * 16) * 32 + ko];
#pragma unroll
            for (int n = 0; n < 4; n++) bf[n] = *(short8*)&c2[4096 + (browf + n * 16) * 32 + ko];
            __builtin_amdgcn_s_setprio(1);
#pragma unroll
            for (int m = 0; m < 4; m++)
#pragma unroll
                for (int n = 0; n < 4; n++)
                    acc[m][n] = __builtin_amdgcn_mfma_f32_16x16x32_bf16(af[m], bf[n], acc[m][n], 0, 0, 0);
            __builtin_amdgcn_s_setprio(0);
        }
        LGKM0;
        __builtin_amdgcn_s_barrier();
    }
    __syncthreads();

    // Epilogue: y chunk (bf16) via Hs transpose
#pragma unroll
    for (int m = 0; m < 4; m++)
#pragma unroll
        for (int n = 0; n < 4; n++)
#pragma unroll
            for (int r = 0; r < 4; r++)
                sm.Hs[(wm * 64 + m * 16 + quad * 4 + r) * 136 + wn * 64 + n * 16 + l15] =
                    f2bf(acc[m][n][r]);
    __syncthreads();
#pragma unroll
    for (int it = 0; it < 8; it++) {
        int s = it * 256 + tid;
        int row = s >> 4, c16 = s & 15;
        if (row < mval)
            *(int4*)(y + (size_t)(row0 + row) * C_DIM + p * 128 + c16 * 8) =
                *(int4*)&sm.Hs[row * 136 + c16 * 8];
    }
}

// Combine: out[t][:] = g0*y[row(2t)][:] + g1*y[row(2t+1)][:]  (fp32 out)
__global__ __launch_bounds__(256) void combine_kernel(
    const unsigned short* __restrict__ y, const int* __restrict__ as_row,
    const float* __restrict__ as_gate, float* __restrict__ out) {
    int tid = threadIdx.x, lane = tid & 63;
    int t = blockIdx.x * 4 + (tid >> 6);
    int r0 = as_row[2 * t], r1 = as_row[2 * t + 1];
    float g0 = as_gate[2 * t], g1 = as_gate[2 * t + 1];
    uint2 a = *(const uint2*)(y + (size_t)r0 * C_DIM + lane * 4);
    uint2 b = *(const uint2*)(y + (size_t)r1 * C_DIM + lane * 4);
    float4 o;
    o.x = g0 * bf2f((unsigned short)(a.x & 0xffff)) + g1 * bf2f((unsigned short)(b.x & 0xffff));
    o.y = g0 * bf2f((unsigned short)(a.x >> 16)) + g1 * bf2f((unsigned short)(b.x >> 16));
    o.z = g0 * bf2f((unsigned short)(a.y & 0xffff)) + g1 * bf2f((unsigned short)(b.y & 0xffff));
    o.w = g0 * bf2f((unsigned short)(a.y >> 16)) + g1 * bf2f((unsigned short)(b.y >> 16));
    *(float4*)(out + (size_t)t * C_DIM + lane * 4) = o;
}

extern "C" void kernel_launch(void* const* d_in, const int* in_sizes, int n_in,
                              void* d_out, int out_size, void* d_ws, size_t ws_size,
                              hipStream_t stream) {
    const float* x = (const float*)d_in[0];
    const float* rw = (const float*)d_in[1];
    const float* w1 = (const float*)d_in[2];
    const float* w2 = (const float*)d_in[3];
    const float* w3 = (const float*)d_in[4];
    float* out = (float*)d_out;

    char* ws = (char*)d_ws;
    size_t o = 0;
    auto alloc = [&](size_t bytes) {
        void* p = ws + o;
        o = (o + bytes + 255) & ~(size_t)255;
        return p;
    };
    unsigned short* xb = (unsigned short*)alloc((size_t)N_TOK * C_DIM * 2);
    unsigned short* w1b = (unsigned short*)alloc((size_t)E_NUM * H_PAD * C_DIM * 2);
    unsigned short* w3b = (unsigned short*)alloc((size_t)E_NUM * H_PAD * C_DIM * 2);
    unsigned short* w2b = (unsigned short*)alloc((size_t)E_NUM * C_DIM * H_PAD * 2);
    unsigned short* hbuf = (unsigned short*)alloc((size_t)(NROWS + 128) * H_PAD * 2);
    unsigned short* ybuf = (unsigned short*)alloc((size_t)NROWS * C_DIM * 2);
    int* offsets = (int*)alloc((E_NUM + 1) * 4);
    int* tile_base = (int*)alloc((E_NUM + 1) * 4);
    int* as_e = (int*)alloc(NROWS * 4);
    float* as_gate = (float*)alloc(NROWS * 4);
    int* row_token = (int*)alloc(NROWS * 4);
    int* as_row = (int*)alloc(NROWS * 4);
    int* block_hist = (int*)alloc(HB * E_NUM * 4);
    int* block_base = (int*)alloc(HB * E_NUM * 4);

    prep_kernel<<<WCONV_BLKS + N_TOK / 4, 256, 0, stream>>>(
        w1, w3, w2, w1b, w3b, w2b, x, rw, xb, as_e, as_gate);
    hist_kernel<<<HB, 256, 0, stream>>>(as_e, block_hist);
    scan2_kernel<<<1, 64, 0, stream>>>(block_hist, offsets, block_base, tile_base);
    scatter_kernel<<<HB, 256, 0, stream>>>(as_e, block_base, row_token, as_row);

    expert_ffn1<<<6 * MAXTILE, 256, 0, stream>>>(xb, w1b, w3b, offsets, tile_base,
                                                 row_token, hbuf);
    expert_ffn2<<<2 * MAXTILE, 256, 0, stream>>>(hbuf, w2b, offsets, tile_base, ybuf);
    combine_kernel<<<N_TOK / 4, 256, 0, stream>>>(ybuf, as_row, as_gate, out);
}